// Round 16
// baseline (391.783 us; speedup 1.0000x reference)
//
#include <hip/hip_runtime.h>
#include <math.h>

namespace {
constexpr int LSEQ = 32;
constexpr int CDIM = 64;
constexpr int HDIM = 128;
constexpr int FDIM = 32;
constexpr float TWO_PI = 6.28318530717958647692f;

typedef float fv2 __attribute__((ext_vector_type(2)));
typedef float fv4 __attribute__((ext_vector_type(4)));

__device__ __forceinline__ float sigf(float x) { return 1.0f / (1.0f + __expf(-x)); }
__device__ __forceinline__ float tanh_fast(float x) { return 1.0f - 2.0f / (__expf(2.0f * x) + 1.0f); }
}

// R15 frame (355us) + mogrify shfl-reduce: k-split moved to LOW lane bits
// (x: ks=t&7, k=kk*8+ks; h: ks=t&3, k=kk*4+ks), so the 8/4 partials for one
// output sit in adjacent lanes -> __shfl_xor(1,2[,4]) reduce (DPP/ds_swizzle),
// no spart round-trip, ONE barrier per mogrify phase (10 -> 5 barriers).
// Interleaved k makes the soh broadcast reads span all 32 banks (re-derived:
// bank-start 4ks mod 32, 8 addrs x 4 banks = 32). qreg/rreg re-indexed.
__global__ __launch_bounds__(512, 1)
void sfm_lstm_r16(const float* __restrict__ x,
                  const float* __restrict__ Q, const float* __restrict__ R,
                  const float* __restrict__ Wi, const float* __restrict__ bi,
                  const float* __restrict__ Wg, const float* __restrict__ bg,
                  const float* __restrict__ Wste, const float* __restrict__ bste,
                  const float* __restrict__ Wfre, const float* __restrict__ bfre,
                  const float* __restrict__ Wom, const float* __restrict__ bom,
                  const float* __restrict__ Wo, const float* __restrict__ bo,
                  const float* __restrict__ Wa, const float* __restrict__ ba,
                  const float* __restrict__ Wout, const float* __restrict__ bout,
                  float* __restrict__ out)
{
    const int t = threadIdx.x;
    const int blk = blockIdx.x;

    // soh[320][4]: rows 0..63 = xt, 64..191 = h, 192..319 = c_t  ([dim][seq])
    __shared__ __align__(16) float soh[320][4];
    __shared__ __align__(16) float sit[HDIM][4];
    __shared__ __align__(16) float schat[HDIM][4];
    __shared__ __align__(16) float sfste[HDIM][4];
    __shared__ __align__(16) float sffre[4][FDIM];     // seq-major for fv2 reads
    __shared__ __align__(16) float scosv[4][FDIM];
    __shared__ __align__(16) float ssinv[4][FDIM];
    __shared__ __align__(16) float spart[8192];        // gate/out partials
    __shared__ float swa[FDIM];

    if (t < FDIM) swa[t] = Wa[t];
    soh[64 + (t >> 2)][t & 3] = 0.0f;                  // h = 0

    // state role: (row r7, seq sA), f-pairs packed
    const int r7 = t & 127, sA = t >> 7;
    fv2 re2[FDIM / 2], im2[FDIM / 2];
    #pragma unroll
    for (int j = 0; j < FDIM / 2; ++j) { re2[j] = 0.0f; im2[j] = 0.0f; }

    // mogrify roles: k-split in LOW lane bits, interleaved k
    const int mxc = t >> 3, mxs = t & 7;               // x: col, k = kk*8+ks
    const int mhj = t >> 2, mhs = t & 3;               // h: col, k = kk*4+ks
    float qreg[16], rreg[16];
    #pragma unroll
    for (int kk = 0; kk < 16; ++kk) qreg[kk] = Q[(kk * 8 + mxs) * CDIM + mxc];
    #pragma unroll
    for (int kk = 0; kk < 16; ++kk) rreg[kk] = R[(kk * 4 + mhs) * HDIM + mhj];

    // gate PARTIAL role (t<448): group gg owns cols 4gg..4gg+3, k-slice gks
    const int gks = t / 112, gg = t - gks * 112;
    const int gcol0 = 4 * gg;
    const float* wPt = Wi; int strP = HDIM;
    if      (gcol0 < 128) { wPt = Wi   + gcol0;         strP = HDIM; }
    else if (gcol0 < 256) { wPt = Wg   + (gcol0 - 128); strP = HDIM; }
    else if (gcol0 < 384) { wPt = Wste + (gcol0 - 256); strP = HDIM; }
    else if (gcol0 < 416) { wPt = Wfre + (gcol0 - 384); strP = FDIM; }
    else                  { wPt = Wom  + (gcol0 - 416); strP = FDIM; }
    wPt += (size_t)(48 * gks) * strP;

    // gate REDUCE role (t<448): col = t
    const float* bG = bi; int reg = -1, gcol = 0;
    if      (t < 128) { bG = bi;   gcol = t;       reg = 0; }
    else if (t < 256) { bG = bg;   gcol = t - 128; reg = 1; }
    else if (t < 384) { bG = bste; gcol = t - 256; reg = 2; }
    else if (t < 416) { bG = bfre; gcol = t - 384; reg = 3; }
    else if (t < 448) { bG = bom;  gcol = t - 416; reg = 4; }
    const float gb = (reg >= 0) ? bG[gcol] : 0.0f;

    // out roles: 16 k-slices x 32 col-groups
    const int oks = t >> 5, og = t & 31;
    const float* woPt = Wo + 4 * og + (size_t)(20 * oks) * HDIM;
    const float bo_r = (t < 128) ? bo[t] : 0.0f;

    const float ba0 = ba[0];
    const float* xbase = x + (size_t)blk * 4 * LSEQ * CDIM;
    const int pl = t - 448;                            // prefetch lane (wave 7)

    // prologue: x(ts=0)
    if (t < 256) soh[t & 63][t >> 6] = xbase[((t >> 6) * LSEQ) * CDIM + (t & 63)];
    __syncthreads();

    for (int ts = 0; ts < LSEQ; ++ts) {
        // ---- mogrify x,h,x,h,x : shfl-reduce, ONE barrier per phase ----
        #pragma unroll
        for (int m = 0; m < 5; ++m) {
            if ((m & 1) == 0) {
                // xt = 2*sig(h @ Q) * xt : (c, ks) roles, k = kk*8+ks
                fv2 a01 = 0.0f, a23 = 0.0f;
                #pragma unroll
                for (int kk = 0; kk < 16; ++kk) {
                    const int k = kk * 8 + mxs;
                    const fv4 h4 = *(const fv4*)&soh[64 + k][0];
                    a01 += h4.lo * qreg[kk]; a23 += h4.hi * qreg[kk];
                }
                #pragma unroll
                for (int d = 1; d <= 4; d <<= 1) {
                    a01.x += __shfl_xor(a01.x, d); a01.y += __shfl_xor(a01.y, d);
                    a23.x += __shfl_xor(a23.x, d); a23.y += __shfl_xor(a23.y, d);
                }
                if (mxs == 0) {
                    const fv4 xo = *(const fv4*)&soh[mxc][0];
                    fv4 nx;
                    nx.x = 2.0f * sigf(a01.x) * xo.x;
                    nx.y = 2.0f * sigf(a01.y) * xo.y;
                    nx.z = 2.0f * sigf(a23.x) * xo.z;
                    nx.w = 2.0f * sigf(a23.y) * xo.w;
                    *(fv4*)&soh[mxc][0] = nx;
                }
                __syncthreads();
            } else {
                // h = 2*sig(x @ R) * h : (j, ks) roles, k = kk*4+ks
                fv2 a01 = 0.0f, a23 = 0.0f;
                #pragma unroll
                for (int kk = 0; kk < 16; ++kk) {
                    const int k = kk * 4 + mhs;
                    const fv4 x4 = *(const fv4*)&soh[k][0];
                    a01 += x4.lo * rreg[kk]; a23 += x4.hi * rreg[kk];
                }
                #pragma unroll
                for (int d = 1; d <= 2; d <<= 1) {
                    a01.x += __shfl_xor(a01.x, d); a01.y += __shfl_xor(a01.y, d);
                    a23.x += __shfl_xor(a23.x, d); a23.y += __shfl_xor(a23.y, d);
                }
                if (mhs == 0) {
                    const fv4 ho = *(const fv4*)&soh[64 + mhj][0];
                    fv4 nh;
                    nh.x = 2.0f * sigf(a01.x) * ho.x;
                    nh.y = 2.0f * sigf(a01.y) * ho.y;
                    nh.z = 2.0f * sigf(a23.x) * ho.z;
                    nh.w = 2.0f * sigf(a23.y) * ho.w;
                    *(fv4*)&soh[64 + mhj][0] = nh;
                }
                __syncthreads();
            }
        }

        // ---- gate partials (t<448): 48 float4 loads, 8 pk_fma each ----
        float xn0 = 0.f, xn1 = 0.f, xn2 = 0.f, xn3 = 0.f;
        if (t < 448) {
            fv2 a0_01 = 0.0f, a0_23 = 0.0f, a1_01 = 0.0f, a1_23 = 0.0f;
            fv2 a2_01 = 0.0f, a2_23 = 0.0f, a3_01 = 0.0f, a3_23 = 0.0f;
            const float* wp = wPt;
            const int kb = 48 * gks;
            #pragma unroll 4
            for (int kk = 0; kk < 48; ++kk) {
                const fv4 w4 = *(const fv4*)wp; wp += strP;
                const fv4 i4 = *(const fv4*)&soh[kb + kk][0];
                const fv2 i01 = i4.lo, i23 = i4.hi;
                a0_01 += i01 * w4.x; a0_23 += i23 * w4.x;
                a1_01 += i01 * w4.y; a1_23 += i23 * w4.y;
                a2_01 += i01 * w4.z; a2_23 += i23 * w4.z;
                a3_01 += i01 * w4.w; a3_23 += i23 * w4.w;
            }
            float* sp = &spart[(gks * 448 + gcol0) * 4];
            *(fv2*)(sp)      = a0_01; *(fv2*)(sp + 2)  = a0_23;
            *(fv2*)(sp + 4)  = a1_01; *(fv2*)(sp + 6)  = a1_23;
            *(fv2*)(sp + 8)  = a2_01; *(fv2*)(sp + 10) = a2_23;
            *(fv2*)(sp + 12) = a3_01; *(fv2*)(sp + 14) = a3_23;
        } else if (ts + 1 < LSEQ) {
            xn0 = xbase[(0 * LSEQ + ts + 1) * CDIM + pl];
            xn1 = xbase[(1 * LSEQ + ts + 1) * CDIM + pl];
            xn2 = xbase[(2 * LSEQ + ts + 1) * CDIM + pl];
            xn3 = xbase[(3 * LSEQ + ts + 1) * CDIM + pl];
        }
        __syncthreads();

        // ---- gate reduce (t<448): col t, 4 seqs ----
        if (reg >= 0) {
            fv2 v01 = 0.0f, v23 = 0.0f;
            #pragma unroll
            for (int ks = 0; ks < 4; ++ks) {
                const float* pp = &spart[(ks * 448 + t) * 4];
                v01 += *(const fv2*)pp; v23 += *(const fv2*)(pp + 2);
            }
            const float v0 = v01.x + gb, v1 = v01.y + gb;
            const float v2 = v23.x + gb, v3 = v23.y + gb;
            if (reg == 4) {
                const float o0 = TWO_PI * sigf(v0), o1 = TWO_PI * sigf(v1);
                const float o2 = TWO_PI * sigf(v2), o3 = TWO_PI * sigf(v3);
                scosv[0][gcol] = __cosf(o0); ssinv[0][gcol] = __sinf(o0);
                scosv[1][gcol] = __cosf(o1); ssinv[1][gcol] = __sinf(o1);
                scosv[2][gcol] = __cosf(o2); ssinv[2][gcol] = __sinf(o2);
                scosv[3][gcol] = __cosf(o3); ssinv[3][gcol] = __sinf(o3);
            } else if (reg == 3) {
                sffre[0][gcol] = sigf(v0); sffre[1][gcol] = sigf(v1);
                sffre[2][gcol] = sigf(v2); sffre[3][gcol] = sigf(v3);
            } else {
                float* d = (reg == 0) ? &sit[0][0] : (reg == 1) ? &schat[0][0] : &sfste[0][0];
                *(fv4*)&d[gcol * 4] = (fv4){sigf(v0), sigf(v1), sigf(v2), sigf(v3)};
            }
        }
        __syncthreads();

        // ---- complex state + amplitude @ Wa -> c_t (f-pairs packed) ----
        {
            const float ic = sit[r7][sA] * schat[r7][sA];
            const float fs = sfste[r7][sA];
            float acc = 0.f;
            #pragma unroll
            for (int j = 0; j < FDIM / 2; ++j) {
                const fv2 fr2 = *(const fv2*)&sffre[sA][2 * j];
                const fv2 cv2 = *(const fv2*)&scosv[sA][2 * j];
                const fv2 sv2 = *(const fv2*)&ssinv[sA][2 * j];
                const fv2 ft2 = fr2 * fs;
                re2[j] = ft2 * re2[j] + cv2 * ic;
                im2[j] = ft2 * im2[j] + sv2 * ic;
                const fv2 m2 = re2[j] * re2[j] + im2[j] * im2[j];
                acc = fmaf(sqrtf(m2.x), swa[2 * j], acc);
                acc = fmaf(sqrtf(m2.y), swa[2 * j + 1], acc);
            }
            soh[192 + r7][sA] = tanh_fast(acc + ba0);
        }
        __syncthreads();

        // ---- out partials: 20 float4 loads, 8 pk_fma each ----
        {
            fv2 a0_01 = 0.0f, a0_23 = 0.0f, a1_01 = 0.0f, a1_23 = 0.0f;
            fv2 a2_01 = 0.0f, a2_23 = 0.0f, a3_01 = 0.0f, a3_23 = 0.0f;
            const float* wp = woPt;
            const int kb = 20 * oks;
            #pragma unroll 4
            for (int kk = 0; kk < 20; ++kk) {
                const fv4 w4 = *(const fv4*)wp; wp += HDIM;
                const fv4 i4 = *(const fv4*)&soh[kb + kk][0];
                const fv2 i01 = i4.lo, i23 = i4.hi;
                a0_01 += i01 * w4.x; a0_23 += i23 * w4.x;
                a1_01 += i01 * w4.y; a1_23 += i23 * w4.y;
                a2_01 += i01 * w4.z; a2_23 += i23 * w4.z;
                a3_01 += i01 * w4.w; a3_23 += i23 * w4.w;
            }
            float* sp = &spart[(oks * 128 + 4 * og) * 4];
            *(fv2*)(sp)      = a0_01; *(fv2*)(sp + 2)  = a0_23;
            *(fv2*)(sp + 4)  = a1_01; *(fv2*)(sp + 6)  = a1_23;
            *(fv2*)(sp + 8)  = a2_01; *(fv2*)(sp + 10) = a2_23;
            *(fv2*)(sp + 12) = a3_01; *(fv2*)(sp + 14) = a3_23;
        }
        __syncthreads();

        // ---- out reduce (t<128) + x commit (wave 7) ----
        if (t < 128) {
            fv2 v01 = 0.0f, v23 = 0.0f;
            #pragma unroll
            for (int ks = 0; ks < 16; ++ks) {
                const float* pp = &spart[(ks * 128 + t) * 4];
                v01 += *(const fv2*)pp; v23 += *(const fv2*)(pp + 2);
            }
            const fv4 ct4 = *(const fv4*)&soh[192 + t][0];
            fv4 h4;
            h4.x = sigf(v01.x + bo_r) * tanh_fast(ct4.x);
            h4.y = sigf(v01.y + bo_r) * tanh_fast(ct4.y);
            h4.z = sigf(v23.x + bo_r) * tanh_fast(ct4.z);
            h4.w = sigf(v23.y + bo_r) * tanh_fast(ct4.w);
            *(fv4*)&soh[64 + t][0] = h4;
        } else if (t >= 448 && ts + 1 < LSEQ) {
            soh[pl][0] = xn0; soh[pl][1] = xn1;
            soh[pl][2] = xn2; soh[pl][3] = xn3;
        }
        __syncthreads();
    }

    // ---- out = h_last @ Wout + bout, one wave per sequence ----
    if (t < 256) {
        const int w = t >> 6, l = t & 63;
        float p = soh[64 + l][w] * Wout[l] + soh[128 + l][w] * Wout[64 + l];
        #pragma unroll
        for (int off = 32; off > 0; off >>= 1) p += __shfl_xor(p, off);
        if (l == 0) out[blk * 4 + w] = p + bout[0];
    }
}

extern "C" void kernel_launch(void* const* d_in, const int* in_sizes, int n_in,
                              void* d_out, int out_size, void* d_ws, size_t ws_size,
                              hipStream_t stream) {
    const float* x    = (const float*)d_in[0];
    const float* Q    = (const float*)d_in[1];
    const float* R    = (const float*)d_in[2];
    const float* Wi   = (const float*)d_in[3];
    const float* bi   = (const float*)d_in[4];
    const float* Wg   = (const float*)d_in[5];
    const float* bg   = (const float*)d_in[6];
    const float* Wste = (const float*)d_in[7];
    const float* bste = (const float*)d_in[8];
    const float* Wfre = (const float*)d_in[9];
    const float* bfre = (const float*)d_in[10];
    const float* Wom  = (const float*)d_in[11];
    const float* bom  = (const float*)d_in[12];
    const float* Wo   = (const float*)d_in[13];
    const float* bo   = (const float*)d_in[14];
    const float* Wa   = (const float*)d_in[15];
    const float* ba   = (const float*)d_in[16];
    const float* Wout = (const float*)d_in[17];
    const float* bout = (const float*)d_in[18];
    float* out = (float*)d_out;

    sfm_lstm_r16<<<dim3(256), dim3(512), 0, stream>>>(
        x, Q, R, Wi, bi, Wg, bg, Wste, bste, Wfre, bfre, Wom, bom,
        Wo, bo, Wa, ba, Wout, bout, out);
}

// Round 17
// 360.840 us; speedup vs baseline: 1.0858x; 1.0858x over previous
//
#include <hip/hip_runtime.h>
#include <math.h>

namespace {
constexpr int LSEQ = 32;
constexpr int CDIM = 64;
constexpr int HDIM = 128;
constexpr int FDIM = 32;
constexpr float TWO_PI = 6.28318530717958647692f;

typedef float fv2 __attribute__((ext_vector_type(2)));
typedef float fv4 __attribute__((ext_vector_type(4)));

__device__ __forceinline__ float sigf(float x) { return 1.0f / (1.0f + __expf(-x)); }
__device__ __forceinline__ float tanh_fast(float x) { return 1.0f - 2.0f / (__expf(2.0f * x) + 1.0f); }
}

// R15 frame (355us; R16 shfl-mogrify reverted) + Wi cached in LDS (96 KB,
// loaded once): cuts the per-step gate L2 stream 344->246 KB (-28%). Gate
// roles remapped so Wi-threads are wave-aligned (t 0..127 = waves 0-1,
// gks-major) -> no divergence between LDS and global load paths. spart
// stays keyed by (gks, gcol0); gate-reduce phase unchanged.
__global__ __launch_bounds__(512, 1)
void sfm_lstm_r17(const float* __restrict__ x,
                  const float* __restrict__ Q, const float* __restrict__ R,
                  const float* __restrict__ Wi, const float* __restrict__ bi,
                  const float* __restrict__ Wg, const float* __restrict__ bg,
                  const float* __restrict__ Wste, const float* __restrict__ bste,
                  const float* __restrict__ Wfre, const float* __restrict__ bfre,
                  const float* __restrict__ Wom, const float* __restrict__ bom,
                  const float* __restrict__ Wo, const float* __restrict__ bo,
                  const float* __restrict__ Wa, const float* __restrict__ ba,
                  const float* __restrict__ Wout, const float* __restrict__ bout,
                  float* __restrict__ out)
{
    const int t = threadIdx.x;
    const int blk = blockIdx.x;

    __shared__ float sWi[192 * HDIM];                  // 96 KB Wi cache
    // soh[320][4]: rows 0..63 = xt, 64..191 = h, 192..319 = c_t  ([dim][seq])
    __shared__ __align__(16) float soh[320][4];
    __shared__ __align__(16) float sit[HDIM][4];
    __shared__ __align__(16) float schat[HDIM][4];
    __shared__ __align__(16) float sfste[HDIM][4];
    __shared__ __align__(16) float sffre[4][FDIM];     // seq-major for fv2 reads
    __shared__ __align__(16) float scosv[4][FDIM];
    __shared__ __align__(16) float ssinv[4][FDIM];
    __shared__ __align__(16) float spart[8192];        // 32 KB partials
    __shared__ float swa[FDIM];

    #pragma unroll
    for (int i = 0; i < 48; ++i) sWi[t + 512 * i] = Wi[t + 512 * i];
    if (t < FDIM) swa[t] = Wa[t];
    soh[64 + (t >> 2)][t & 3] = 0.0f;                  // h = 0

    // state role: (row r7, seq sA), f-pairs packed
    const int r7 = t & 127, sA = t >> 7;
    fv2 re2[FDIM / 2], im2[FDIM / 2];
    #pragma unroll
    for (int j = 0; j < FDIM / 2; ++j) { re2[j] = 0.0f; im2[j] = 0.0f; }

    // mogrify roles + register-cached per-lane weight slices (R15-verbatim)
    const int mc = t & 63,  mksx = t >> 6;             // x: col mc, 8 k-slices of 16
    const int mj = t & 127, mksh = t >> 7;             // h: col mj, 4 k-slices of 16
    float qreg[16], rreg[16];
    #pragma unroll
    for (int kk = 0; kk < 16; ++kk) qreg[kk] = Q[(mksx * 16 + kk) * CDIM + mc];
    #pragma unroll
    for (int kk = 0; kk < 16; ++kk) rreg[kk] = R[(mksh * 16 + kk) * HDIM + mj];

    // gate PARTIAL role: wave-aligned matrix split, gks-major within matrix.
    //   t   0..127: Wi   (LDS path), gks = (t&127)>>5, gcol0 = 4*(t&31)
    //   t 128..255: Wg,  t 256..383: Wste  (gks = (i&127)>>5, col 4*(i&31))
    //   t 384..447: Wfre/Wom (gks = i>>4, 16 col-groups)
    int gks = 0, gcol0 = 0;
    const float* wPt = Wg; int strP = HDIM;
    if (t < 128) {
        gks = t >> 5; gcol0 = 4 * (t & 31);
    } else if (t < 256) {
        const int i2 = t - 128; gks = i2 >> 5; gcol0 = 128 + 4 * (i2 & 31);
        wPt = Wg + (gcol0 - 128) + (size_t)(48 * gks) * HDIM;
    } else if (t < 384) {
        const int i2 = t - 256; gks = i2 >> 5; gcol0 = 256 + 4 * (i2 & 31);
        wPt = Wste + (gcol0 - 256) + (size_t)(48 * gks) * HDIM;
    } else if (t < 448) {
        const int i2 = t - 384; gks = i2 >> 4; const int gg = i2 & 15;
        gcol0 = 384 + 4 * gg;
        if (gcol0 < 416) { wPt = Wfre + (gcol0 - 384) + (size_t)(48 * gks) * FDIM; strP = FDIM; }
        else             { wPt = Wom  + (gcol0 - 416) + (size_t)(48 * gks) * FDIM; strP = FDIM; }
    }
    const float* swiP = &sWi[(48 * gks) * HDIM + gcol0];

    // gate REDUCE role (t<448): col = t (spart layout unchanged)
    const float* bG = bi; int reg = -1, gcol = 0;
    if      (t < 128) { bG = bi;   gcol = t;       reg = 0; }
    else if (t < 256) { bG = bg;   gcol = t - 128; reg = 1; }
    else if (t < 384) { bG = bste; gcol = t - 256; reg = 2; }
    else if (t < 416) { bG = bfre; gcol = t - 384; reg = 3; }
    else if (t < 448) { bG = bom;  gcol = t - 416; reg = 4; }
    const float gb = (reg >= 0) ? bG[gcol] : 0.0f;

    // out roles: 16 k-slices x 32 col-groups
    const int oks = t >> 5, og = t & 31;
    const float* woPt = Wo + 4 * og + (size_t)(20 * oks) * HDIM;
    const float bo_r = (t < 128) ? bo[t] : 0.0f;

    const float ba0 = ba[0];
    const float* xbase = x + (size_t)blk * 4 * LSEQ * CDIM;
    const int pl = t - 448;                            // prefetch lane (wave 7)

    // prologue: x(ts=0)
    if (t < 256) soh[t & 63][t >> 6] = xbase[((t >> 6) * LSEQ) * CDIM + (t & 63)];
    __syncthreads();

    for (int ts = 0; ts < LSEQ; ++ts) {
        // ---- mogrify x,h,x,h,x (weights in registers, pk_fma packed) ----
        #pragma unroll
        for (int m = 0; m < 5; ++m) {
            if ((m & 1) == 0) {
                const int k0 = mksx * 16;
                fv2 a01 = 0.0f, a23 = 0.0f;
                #pragma unroll
                for (int kk = 0; kk < 16; ++kk) {
                    const fv4 h4 = *(const fv4*)&soh[64 + k0 + kk][0];
                    a01 += h4.lo * qreg[kk]; a23 += h4.hi * qreg[kk];
                }
                float* sp = &spart[mksx * 256 + mc * 4];
                *(fv2*)(sp) = a01; *(fv2*)(sp + 2) = a23;
                __syncthreads();
                if (t < 256) {
                    float v = 0.f;
                    #pragma unroll
                    for (int i = 0; i < 8; ++i) v += spart[i * 256 + t];
                    soh[t >> 2][t & 3] = 2.0f * sigf(v) * soh[t >> 2][t & 3];
                }
                __syncthreads();
            } else {
                const int k0 = mksh * 16;
                fv2 a01 = 0.0f, a23 = 0.0f;
                #pragma unroll
                for (int kk = 0; kk < 16; ++kk) {
                    const fv4 x4 = *(const fv4*)&soh[k0 + kk][0];
                    a01 += x4.lo * rreg[kk]; a23 += x4.hi * rreg[kk];
                }
                float* sp = &spart[mksh * 512 + mj * 4];
                *(fv2*)(sp) = a01; *(fv2*)(sp + 2) = a23;
                __syncthreads();
                {
                    const float v = spart[t] + spart[512 + t] + spart[1024 + t] + spart[1536 + t];
                    soh[64 + (t >> 2)][t & 3] = 2.0f * sigf(v) * soh[64 + (t >> 2)][t & 3];
                }
                __syncthreads();
            }
        }

        // ---- gate partials: Wi waves read LDS, rest stream L2 ----
        float xn0 = 0.f, xn1 = 0.f, xn2 = 0.f, xn3 = 0.f;
        if (t < 128) {
            // Wi path: weights from LDS cache
            fv2 a0_01 = 0.0f, a0_23 = 0.0f, a1_01 = 0.0f, a1_23 = 0.0f;
            fv2 a2_01 = 0.0f, a2_23 = 0.0f, a3_01 = 0.0f, a3_23 = 0.0f;
            const float* wp = swiP;
            const int kb = 48 * gks;
            #pragma unroll 4
            for (int kk = 0; kk < 48; ++kk) {
                const fv4 w4 = *(const fv4*)wp; wp += HDIM;
                const fv4 i4 = *(const fv4*)&soh[kb + kk][0];
                const fv2 i01 = i4.lo, i23 = i4.hi;
                a0_01 += i01 * w4.x; a0_23 += i23 * w4.x;
                a1_01 += i01 * w4.y; a1_23 += i23 * w4.y;
                a2_01 += i01 * w4.z; a2_23 += i23 * w4.z;
                a3_01 += i01 * w4.w; a3_23 += i23 * w4.w;
            }
            float* sp = &spart[(gks * 448 + gcol0) * 4];
            *(fv2*)(sp)      = a0_01; *(fv2*)(sp + 2)  = a0_23;
            *(fv2*)(sp + 4)  = a1_01; *(fv2*)(sp + 6)  = a1_23;
            *(fv2*)(sp + 8)  = a2_01; *(fv2*)(sp + 10) = a2_23;
            *(fv2*)(sp + 12) = a3_01; *(fv2*)(sp + 14) = a3_23;
        } else if (t < 448) {
            fv2 a0_01 = 0.0f, a0_23 = 0.0f, a1_01 = 0.0f, a1_23 = 0.0f;
            fv2 a2_01 = 0.0f, a2_23 = 0.0f, a3_01 = 0.0f, a3_23 = 0.0f;
            const float* wp = wPt;
            const int kb = 48 * gks;
            #pragma unroll 4
            for (int kk = 0; kk < 48; ++kk) {
                const fv4 w4 = *(const fv4*)wp; wp += strP;
                const fv4 i4 = *(const fv4*)&soh[kb + kk][0];
                const fv2 i01 = i4.lo, i23 = i4.hi;
                a0_01 += i01 * w4.x; a0_23 += i23 * w4.x;
                a1_01 += i01 * w4.y; a1_23 += i23 * w4.y;
                a2_01 += i01 * w4.z; a2_23 += i23 * w4.z;
                a3_01 += i01 * w4.w; a3_23 += i23 * w4.w;
            }
            float* sp = &spart[(gks * 448 + gcol0) * 4];
            *(fv2*)(sp)      = a0_01; *(fv2*)(sp + 2)  = a0_23;
            *(fv2*)(sp + 4)  = a1_01; *(fv2*)(sp + 6)  = a1_23;
            *(fv2*)(sp + 8)  = a2_01; *(fv2*)(sp + 10) = a2_23;
            *(fv2*)(sp + 12) = a3_01; *(fv2*)(sp + 14) = a3_23;
        } else if (ts + 1 < LSEQ) {
            xn0 = xbase[(0 * LSEQ + ts + 1) * CDIM + pl];
            xn1 = xbase[(1 * LSEQ + ts + 1) * CDIM + pl];
            xn2 = xbase[(2 * LSEQ + ts + 1) * CDIM + pl];
            xn3 = xbase[(3 * LSEQ + ts + 1) * CDIM + pl];
        }
        __syncthreads();

        // ---- gate reduce (t<448): col t, 4 seqs ----
        if (reg >= 0) {
            fv2 v01 = 0.0f, v23 = 0.0f;
            #pragma unroll
            for (int ks = 0; ks < 4; ++ks) {
                const float* pp = &spart[(ks * 448 + t) * 4];
                v01 += *(const fv2*)pp; v23 += *(const fv2*)(pp + 2);
            }
            const float v0 = v01.x + gb, v1 = v01.y + gb;
            const float v2 = v23.x + gb, v3 = v23.y + gb;
            if (reg == 4) {
                const float o0 = TWO_PI * sigf(v0), o1 = TWO_PI * sigf(v1);
                const float o2 = TWO_PI * sigf(v2), o3 = TWO_PI * sigf(v3);
                scosv[0][gcol] = __cosf(o0); ssinv[0][gcol] = __sinf(o0);
                scosv[1][gcol] = __cosf(o1); ssinv[1][gcol] = __sinf(o1);
                scosv[2][gcol] = __cosf(o2); ssinv[2][gcol] = __sinf(o2);
                scosv[3][gcol] = __cosf(o3); ssinv[3][gcol] = __sinf(o3);
            } else if (reg == 3) {
                sffre[0][gcol] = sigf(v0); sffre[1][gcol] = sigf(v1);
                sffre[2][gcol] = sigf(v2); sffre[3][gcol] = sigf(v3);
            } else {
                float* d = (reg == 0) ? &sit[0][0] : (reg == 1) ? &schat[0][0] : &sfste[0][0];
                *(fv4*)&d[gcol * 4] = (fv4){sigf(v0), sigf(v1), sigf(v2), sigf(v3)};
            }
        }
        __syncthreads();

        // ---- complex state + amplitude @ Wa -> c_t (f-pairs packed) ----
        {
            const float ic = sit[r7][sA] * schat[r7][sA];
            const float fs = sfste[r7][sA];
            float acc = 0.f;
            #pragma unroll
            for (int j = 0; j < FDIM / 2; ++j) {
                const fv2 fr2 = *(const fv2*)&sffre[sA][2 * j];
                const fv2 cv2 = *(const fv2*)&scosv[sA][2 * j];
                const fv2 sv2 = *(const fv2*)&ssinv[sA][2 * j];
                const fv2 ft2 = fr2 * fs;
                re2[j] = ft2 * re2[j] + cv2 * ic;
                im2[j] = ft2 * im2[j] + sv2 * ic;
                const fv2 m2 = re2[j] * re2[j] + im2[j] * im2[j];
                acc = fmaf(sqrtf(m2.x), swa[2 * j], acc);
                acc = fmaf(sqrtf(m2.y), swa[2 * j + 1], acc);
            }
            soh[192 + r7][sA] = tanh_fast(acc + ba0);
        }
        __syncthreads();

        // ---- out partials: 20 float4 loads, 8 pk_fma each ----
        {
            fv2 a0_01 = 0.0f, a0_23 = 0.0f, a1_01 = 0.0f, a1_23 = 0.0f;
            fv2 a2_01 = 0.0f, a2_23 = 0.0f, a3_01 = 0.0f, a3_23 = 0.0f;
            const float* wp = woPt;
            const int kb = 20 * oks;
            #pragma unroll 4
            for (int kk = 0; kk < 20; ++kk) {
                const fv4 w4 = *(const fv4*)wp; wp += HDIM;
                const fv4 i4 = *(const fv4*)&soh[kb + kk][0];
                const fv2 i01 = i4.lo, i23 = i4.hi;
                a0_01 += i01 * w4.x; a0_23 += i23 * w4.x;
                a1_01 += i01 * w4.y; a1_23 += i23 * w4.y;
                a2_01 += i01 * w4.z; a2_23 += i23 * w4.z;
                a3_01 += i01 * w4.w; a3_23 += i23 * w4.w;
            }
            float* sp = &spart[(oks * 128 + 4 * og) * 4];
            *(fv2*)(sp)      = a0_01; *(fv2*)(sp + 2)  = a0_23;
            *(fv2*)(sp + 4)  = a1_01; *(fv2*)(sp + 6)  = a1_23;
            *(fv2*)(sp + 8)  = a2_01; *(fv2*)(sp + 10) = a2_23;
            *(fv2*)(sp + 12) = a3_01; *(fv2*)(sp + 14) = a3_23;
        }
        __syncthreads();

        // ---- out reduce (t<128) + x commit (wave 7) ----
        if (t < 128) {
            fv2 v01 = 0.0f, v23 = 0.0f;
            #pragma unroll
            for (int ks = 0; ks < 16; ++ks) {
                const float* pp = &spart[(ks * 128 + t) * 4];
                v01 += *(const fv2*)pp; v23 += *(const fv2*)(pp + 2);
            }
            const fv4 ct4 = *(const fv4*)&soh[192 + t][0];
            fv4 h4;
            h4.x = sigf(v01.x + bo_r) * tanh_fast(ct4.x);
            h4.y = sigf(v01.y + bo_r) * tanh_fast(ct4.y);
            h4.z = sigf(v23.x + bo_r) * tanh_fast(ct4.z);
            h4.w = sigf(v23.y + bo_r) * tanh_fast(ct4.w);
            *(fv4*)&soh[64 + t][0] = h4;
        } else if (t >= 448 && ts + 1 < LSEQ) {
            soh[pl][0] = xn0; soh[pl][1] = xn1;
            soh[pl][2] = xn2; soh[pl][3] = xn3;
        }
        __syncthreads();
    }

    // ---- out = h_last @ Wout + bout, one wave per sequence ----
    if (t < 256) {
        const int w = t >> 6, l = t & 63;
        float p = soh[64 + l][w] * Wout[l] + soh[128 + l][w] * Wout[64 + l];
        #pragma unroll
        for (int off = 32; off > 0; off >>= 1) p += __shfl_xor(p, off);
        if (l == 0) out[blk * 4 + w] = p + bout[0];
    }
}

extern "C" void kernel_launch(void* const* d_in, const int* in_sizes, int n_in,
                              void* d_out, int out_size, void* d_ws, size_t ws_size,
                              hipStream_t stream) {
    const float* x    = (const float*)d_in[0];
    const float* Q    = (const float*)d_in[1];
    const float* R    = (const float*)d_in[2];
    const float* Wi   = (const float*)d_in[3];
    const float* bi   = (const float*)d_in[4];
    const float* Wg   = (const float*)d_in[5];
    const float* bg   = (const float*)d_in[6];
    const float* Wste = (const float*)d_in[7];
    const float* bste = (const float*)d_in[8];
    const float* Wfre = (const float*)d_in[9];
    const float* bfre = (const float*)d_in[10];
    const float* Wom  = (const float*)d_in[11];
    const float* bom  = (const float*)d_in[12];
    const float* Wo   = (const float*)d_in[13];
    const float* bo   = (const float*)d_in[14];
    const float* Wa   = (const float*)d_in[15];
    const float* ba   = (const float*)d_in[16];
    const float* Wout = (const float*)d_in[17];
    const float* bout = (const float*)d_in[18];
    float* out = (float*)d_out;

    sfm_lstm_r17<<<dim3(256), dim3(512), 0, stream>>>(
        x, Q, R, Wi, bi, Wg, bg, Wste, bste, Wfre, bfre, Wom, bom,
        Wo, bo, Wa, ba, Wout, bout, out);
}

// Round 18
// 356.511 us; speedup vs baseline: 1.0989x; 1.0121x over previous
//
#include <hip/hip_runtime.h>
#include <math.h>

namespace {
constexpr int LSEQ = 32;
constexpr int CDIM = 64;
constexpr int HDIM = 128;
constexpr int FDIM = 32;
constexpr float TWO_PI = 6.28318530717958647692f;

typedef float fv2 __attribute__((ext_vector_type(2)));
typedef float fv4 __attribute__((ext_vector_type(4)));

__device__ __forceinline__ float sigf(float x) { return 1.0f / (1.0f + __expf(-x)); }
__device__ __forceinline__ float tanh_fast(float x) { return 1.0f - 2.0f / (__expf(2.0f * x) + 1.0f); }
}

// FINAL FRAME (R15, 355us): S=4 seqs/block, 256 blocks (1/CU), 512 threads.
// - pk_fma (fv2/fv4) packing on all seq-pair accumulations (R13)
// - mogrify weights in registers qreg[16]/rreg[16] (per-lane-constant Q/R
//   slices), no LDS weight reads on the serial mogrify chain (R15)
// - float4 weight streams for gates (48/thread) and out (20/thread) (R9)
// - x(ts+1) register-prefetched by the gate-idle wave 7 (R4 lineage)
// Platform laws (measured): VGPR cap = 65536/blockDim; 1024-thr blocks pin
// 64 VGPR; exactly 1 workgroup/CU co-resides regardless of LDS. These close
// all occupancy routes; kernel is serial-phase/barrier-latency bound.
__global__ __launch_bounds__(512, 1)
void sfm_lstm_r18(const float* __restrict__ x,
                  const float* __restrict__ Q, const float* __restrict__ R,
                  const float* __restrict__ Wi, const float* __restrict__ bi,
                  const float* __restrict__ Wg, const float* __restrict__ bg,
                  const float* __restrict__ Wste, const float* __restrict__ bste,
                  const float* __restrict__ Wfre, const float* __restrict__ bfre,
                  const float* __restrict__ Wom, const float* __restrict__ bom,
                  const float* __restrict__ Wo, const float* __restrict__ bo,
                  const float* __restrict__ Wa, const float* __restrict__ ba,
                  const float* __restrict__ Wout, const float* __restrict__ bout,
                  float* __restrict__ out)
{
    const int t = threadIdx.x;
    const int blk = blockIdx.x;

    // soh[320][4]: rows 0..63 = xt, 64..191 = h, 192..319 = c_t  ([dim][seq])
    __shared__ __align__(16) float soh[320][4];
    __shared__ __align__(16) float sit[HDIM][4];
    __shared__ __align__(16) float schat[HDIM][4];
    __shared__ __align__(16) float sfste[HDIM][4];
    __shared__ __align__(16) float sffre[4][FDIM];     // seq-major for fv2 reads
    __shared__ __align__(16) float scosv[4][FDIM];
    __shared__ __align__(16) float ssinv[4][FDIM];
    __shared__ __align__(16) float spart[8192];        // 32 KB partials
    __shared__ float swa[FDIM];

    if (t < FDIM) swa[t] = Wa[t];
    soh[64 + (t >> 2)][t & 3] = 0.0f;                  // h = 0

    // state role: (row r7, seq sA), f-pairs packed
    const int r7 = t & 127, sA = t >> 7;
    fv2 re2[FDIM / 2], im2[FDIM / 2];
    #pragma unroll
    for (int j = 0; j < FDIM / 2; ++j) { re2[j] = 0.0f; im2[j] = 0.0f; }

    // mogrify roles + register-cached per-lane weight slices
    const int mc = t & 63,  mksx = t >> 6;             // x: col mc, 8 k-slices of 16
    const int mj = t & 127, mksh = t >> 7;             // h: col mj, 4 k-slices of 16
    float qreg[16], rreg[16];
    #pragma unroll
    for (int kk = 0; kk < 16; ++kk) qreg[kk] = Q[(mksx * 16 + kk) * CDIM + mc];
    #pragma unroll
    for (int kk = 0; kk < 16; ++kk) rreg[kk] = R[(mksh * 16 + kk) * HDIM + mj];

    // gate PARTIAL role (t<448): group gg owns cols 4gg..4gg+3, k-slice gks
    const int gks = t / 112, gg = t - gks * 112;
    const int gcol0 = 4 * gg;
    const float* wPt = Wi; int strP = HDIM;
    if      (gcol0 < 128) { wPt = Wi   + gcol0;         strP = HDIM; }
    else if (gcol0 < 256) { wPt = Wg   + (gcol0 - 128); strP = HDIM; }
    else if (gcol0 < 384) { wPt = Wste + (gcol0 - 256); strP = HDIM; }
    else if (gcol0 < 416) { wPt = Wfre + (gcol0 - 384); strP = FDIM; }
    else                  { wPt = Wom  + (gcol0 - 416); strP = FDIM; }
    wPt += (size_t)(48 * gks) * strP;

    // gate REDUCE role (t<448): col = t
    const float* bG = bi; int reg = -1, gcol = 0;
    if      (t < 128) { bG = bi;   gcol = t;       reg = 0; }
    else if (t < 256) { bG = bg;   gcol = t - 128; reg = 1; }
    else if (t < 384) { bG = bste; gcol = t - 256; reg = 2; }
    else if (t < 416) { bG = bfre; gcol = t - 384; reg = 3; }
    else if (t < 448) { bG = bom;  gcol = t - 416; reg = 4; }
    const float gb = (reg >= 0) ? bG[gcol] : 0.0f;

    // out roles: 16 k-slices x 32 col-groups
    const int oks = t >> 5, og = t & 31;
    const float* woPt = Wo + 4 * og + (size_t)(20 * oks) * HDIM;
    const float bo_r = (t < 128) ? bo[t] : 0.0f;

    const float ba0 = ba[0];
    const float* xbase = x + (size_t)blk * 4 * LSEQ * CDIM;
    const int pl = t - 448;                            // prefetch lane (wave 7)

    // prologue: x(ts=0)
    if (t < 256) soh[t & 63][t >> 6] = xbase[((t >> 6) * LSEQ) * CDIM + (t & 63)];
    __syncthreads();

    for (int ts = 0; ts < LSEQ; ++ts) {
        // ---- mogrify x,h,x,h,x (weights in registers, pk_fma packed) ----
        #pragma unroll
        for (int m = 0; m < 5; ++m) {
            if ((m & 1) == 0) {
                const int k0 = mksx * 16;
                fv2 a01 = 0.0f, a23 = 0.0f;
                #pragma unroll
                for (int kk = 0; kk < 16; ++kk) {
                    const fv4 h4 = *(const fv4*)&soh[64 + k0 + kk][0];
                    a01 += h4.lo * qreg[kk]; a23 += h4.hi * qreg[kk];
                }
                float* sp = &spart[mksx * 256 + mc * 4];
                *(fv2*)(sp) = a01; *(fv2*)(sp + 2) = a23;
                __syncthreads();
                if (t < 256) {
                    float v = 0.f;
                    #pragma unroll
                    for (int i = 0; i < 8; ++i) v += spart[i * 256 + t];
                    soh[t >> 2][t & 3] = 2.0f * sigf(v) * soh[t >> 2][t & 3];
                }
                __syncthreads();
            } else {
                const int k0 = mksh * 16;
                fv2 a01 = 0.0f, a23 = 0.0f;
                #pragma unroll
                for (int kk = 0; kk < 16; ++kk) {
                    const fv4 x4 = *(const fv4*)&soh[k0 + kk][0];
                    a01 += x4.lo * rreg[kk]; a23 += x4.hi * rreg[kk];
                }
                float* sp = &spart[mksh * 512 + mj * 4];
                *(fv2*)(sp) = a01; *(fv2*)(sp + 2) = a23;
                __syncthreads();
                {
                    const float v = spart[t] + spart[512 + t] + spart[1024 + t] + spart[1536 + t];
                    soh[64 + (t >> 2)][t & 3] = 2.0f * sigf(v) * soh[64 + (t >> 2)][t & 3];
                }
                __syncthreads();
            }
        }

        // ---- gate partials (t<448): 48 float4 loads, 8 pk_fma each ----
        float xn0 = 0.f, xn1 = 0.f, xn2 = 0.f, xn3 = 0.f;
        if (t < 448) {
            fv2 a0_01 = 0.0f, a0_23 = 0.0f, a1_01 = 0.0f, a1_23 = 0.0f;
            fv2 a2_01 = 0.0f, a2_23 = 0.0f, a3_01 = 0.0f, a3_23 = 0.0f;
            const float* wp = wPt;
            const int kb = 48 * gks;
            #pragma unroll 4
            for (int kk = 0; kk < 48; ++kk) {
                const fv4 w4 = *(const fv4*)wp; wp += strP;
                const fv4 i4 = *(const fv4*)&soh[kb + kk][0];
                const fv2 i01 = i4.lo, i23 = i4.hi;
                a0_01 += i01 * w4.x; a0_23 += i23 * w4.x;
                a1_01 += i01 * w4.y; a1_23 += i23 * w4.y;
                a2_01 += i01 * w4.z; a2_23 += i23 * w4.z;
                a3_01 += i01 * w4.w; a3_23 += i23 * w4.w;
            }
            float* sp = &spart[(gks * 448 + gcol0) * 4];
            *(fv2*)(sp)      = a0_01; *(fv2*)(sp + 2)  = a0_23;
            *(fv2*)(sp + 4)  = a1_01; *(fv2*)(sp + 6)  = a1_23;
            *(fv2*)(sp + 8)  = a2_01; *(fv2*)(sp + 10) = a2_23;
            *(fv2*)(sp + 12) = a3_01; *(fv2*)(sp + 14) = a3_23;
        } else if (ts + 1 < LSEQ) {
            xn0 = xbase[(0 * LSEQ + ts + 1) * CDIM + pl];
            xn1 = xbase[(1 * LSEQ + ts + 1) * CDIM + pl];
            xn2 = xbase[(2 * LSEQ + ts + 1) * CDIM + pl];
            xn3 = xbase[(3 * LSEQ + ts + 1) * CDIM + pl];
        }
        __syncthreads();

        // ---- gate reduce (t<448): col t, 4 seqs ----
        if (reg >= 0) {
            fv2 v01 = 0.0f, v23 = 0.0f;
            #pragma unroll
            for (int ks = 0; ks < 4; ++ks) {
                const float* pp = &spart[(ks * 448 + t) * 4];
                v01 += *(const fv2*)pp; v23 += *(const fv2*)(pp + 2);
            }
            const float v0 = v01.x + gb, v1 = v01.y + gb;
            const float v2 = v23.x + gb, v3 = v23.y + gb;
            if (reg == 4) {
                const float o0 = TWO_PI * sigf(v0), o1 = TWO_PI * sigf(v1);
                const float o2 = TWO_PI * sigf(v2), o3 = TWO_PI * sigf(v3);
                scosv[0][gcol] = __cosf(o0); ssinv[0][gcol] = __sinf(o0);
                scosv[1][gcol] = __cosf(o1); ssinv[1][gcol] = __sinf(o1);
                scosv[2][gcol] = __cosf(o2); ssinv[2][gcol] = __sinf(o2);
                scosv[3][gcol] = __cosf(o3); ssinv[3][gcol] = __sinf(o3);
            } else if (reg == 3) {
                sffre[0][gcol] = sigf(v0); sffre[1][gcol] = sigf(v1);
                sffre[2][gcol] = sigf(v2); sffre[3][gcol] = sigf(v3);
            } else {
                float* d = (reg == 0) ? &sit[0][0] : (reg == 1) ? &schat[0][0] : &sfste[0][0];
                *(fv4*)&d[gcol * 4] = (fv4){sigf(v0), sigf(v1), sigf(v2), sigf(v3)};
            }
        }
        __syncthreads();

        // ---- complex state + amplitude @ Wa -> c_t (f-pairs packed) ----
        {
            const float ic = sit[r7][sA] * schat[r7][sA];
            const float fs = sfste[r7][sA];
            float acc = 0.f;
            #pragma unroll
            for (int j = 0; j < FDIM / 2; ++j) {
                const fv2 fr2 = *(const fv2*)&sffre[sA][2 * j];
                const fv2 cv2 = *(const fv2*)&scosv[sA][2 * j];
                const fv2 sv2 = *(const fv2*)&ssinv[sA][2 * j];
                const fv2 ft2 = fr2 * fs;
                re2[j] = ft2 * re2[j] + cv2 * ic;
                im2[j] = ft2 * im2[j] + sv2 * ic;
                const fv2 m2 = re2[j] * re2[j] + im2[j] * im2[j];
                acc = fmaf(sqrtf(m2.x), swa[2 * j], acc);
                acc = fmaf(sqrtf(m2.y), swa[2 * j + 1], acc);
            }
            soh[192 + r7][sA] = tanh_fast(acc + ba0);
        }
        __syncthreads();

        // ---- out partials: 20 float4 loads, 8 pk_fma each ----
        {
            fv2 a0_01 = 0.0f, a0_23 = 0.0f, a1_01 = 0.0f, a1_23 = 0.0f;
            fv2 a2_01 = 0.0f, a2_23 = 0.0f, a3_01 = 0.0f, a3_23 = 0.0f;
            const float* wp = woPt;
            const int kb = 20 * oks;
            #pragma unroll 4
            for (int kk = 0; kk < 20; ++kk) {
                const fv4 w4 = *(const fv4*)wp; wp += HDIM;
                const fv4 i4 = *(const fv4*)&soh[kb + kk][0];
                const fv2 i01 = i4.lo, i23 = i4.hi;
                a0_01 += i01 * w4.x; a0_23 += i23 * w4.x;
                a1_01 += i01 * w4.y; a1_23 += i23 * w4.y;
                a2_01 += i01 * w4.z; a2_23 += i23 * w4.z;
                a3_01 += i01 * w4.w; a3_23 += i23 * w4.w;
            }
            float* sp = &spart[(oks * 128 + 4 * og) * 4];
            *(fv2*)(sp)      = a0_01; *(fv2*)(sp + 2)  = a0_23;
            *(fv2*)(sp + 4)  = a1_01; *(fv2*)(sp + 6)  = a1_23;
            *(fv2*)(sp + 8)  = a2_01; *(fv2*)(sp + 10) = a2_23;
            *(fv2*)(sp + 12) = a3_01; *(fv2*)(sp + 14) = a3_23;
        }
        __syncthreads();

        // ---- out reduce (t<128) + x commit (wave 7) ----
        if (t < 128) {
            fv2 v01 = 0.0f, v23 = 0.0f;
            #pragma unroll
            for (int ks = 0; ks < 16; ++ks) {
                const float* pp = &spart[(ks * 128 + t) * 4];
                v01 += *(const fv2*)pp; v23 += *(const fv2*)(pp + 2);
            }
            const fv4 ct4 = *(const fv4*)&soh[192 + t][0];
            fv4 h4;
            h4.x = sigf(v01.x + bo_r) * tanh_fast(ct4.x);
            h4.y = sigf(v01.y + bo_r) * tanh_fast(ct4.y);
            h4.z = sigf(v23.x + bo_r) * tanh_fast(ct4.z);
            h4.w = sigf(v23.y + bo_r) * tanh_fast(ct4.w);
            *(fv4*)&soh[64 + t][0] = h4;
        } else if (t >= 448 && ts + 1 < LSEQ) {
            soh[pl][0] = xn0; soh[pl][1] = xn1;
            soh[pl][2] = xn2; soh[pl][3] = xn3;
        }
        __syncthreads();
    }

    // ---- out = h_last @ Wout + bout, one wave per sequence ----
    if (t < 256) {
        const int w = t >> 6, l = t & 63;
        float p = soh[64 + l][w] * Wout[l] + soh[128 + l][w] * Wout[64 + l];
        #pragma unroll
        for (int off = 32; off > 0; off >>= 1) p += __shfl_xor(p, off);
        if (l == 0) out[blk * 4 + w] = p + bout[0];
    }
}

extern "C" void kernel_launch(void* const* d_in, const int* in_sizes, int n_in,
                              void* d_out, int out_size, void* d_ws, size_t ws_size,
                              hipStream_t stream) {
    const float* x    = (const float*)d_in[0];
    const float* Q    = (const float*)d_in[1];
    const float* R    = (const float*)d_in[2];
    const float* Wi   = (const float*)d_in[3];
    const float* bi   = (const float*)d_in[4];
    const float* Wg   = (const float*)d_in[5];
    const float* bg   = (const float*)d_in[6];
    const float* Wste = (const float*)d_in[7];
    const float* bste = (const float*)d_in[8];
    const float* Wfre = (const float*)d_in[9];
    const float* bfre = (const float*)d_in[10];
    const float* Wom  = (const float*)d_in[11];
    const float* bom  = (const float*)d_in[12];
    const float* Wo   = (const float*)d_in[13];
    const float* bo   = (const float*)d_in[14];
    const float* Wa   = (const float*)d_in[15];
    const float* ba   = (const float*)d_in[16];
    const float* Wout = (const float*)d_in[17];
    const float* bout = (const float*)d_in[18];
    float* out = (float*)d_out;

    sfm_lstm_r18<<<dim3(256), dim3(512), 0, stream>>>(
        x, Q, R, Wi, bi, Wg, bg, Wste, bste, Wfre, bfre, Wom, bom,
        Wo, bo, Wa, ba, Wout, bout, out);
}